// Round 7
// baseline (20.813 us; speedup 1.0000x reference)
//
#include <hip/hip_runtime.h>
#include <hip/hip_bf16.h>
#include <stdint.h>
#include <math.h>

// Nucleus sampling reduces to row-wise max+argmax:
// the top-p filter never removes the row max (mask is shifted right by one,
// so the first sorted element always survives; stable argsort preserves
// first-occurrence on ties). So output = (argmax(logits,-1), max(logits,-1)).
//
// Output layout (read back as float32):
//   d_out[0 .. S-1]   = tokens (exact integer values as float)
//   d_out[S .. 2S-1]  = scores (float)
//
// R7 = R6 (512 thr/block, 4 chains, nontemporal dwordx4) with the per-float4
// compare cascade (12 dependent VALU ops) replaced by a max3 fast path
// (~4 ops): reduce the vector to its max, compare once vs the running best,
// resolve the intra-vector index only on a record break (rare, exec-masked).
// Isolates the "issue/dep-chain serialization" hypothesis vs R6.

#define BLOCK 512

typedef float floatx4 __attribute__((ext_vector_type(4)));

__device__ __forceinline__ floatx4 ntload(const floatx4* __restrict__ p) {
    return __builtin_nontemporal_load(p);
}

// Update chain (b, idx) with float4 v whose first element has global index k.
// First-occurrence ties: cascade resolves lowest index within the vector;
// strict '>' across vectors keeps the earlier occurrence.
#define CHAIN_STEP(v, k, b, idx)                                             \
    do {                                                                     \
        const float m_ = fmaxf(fmaxf((v).x, (v).y), fmaxf((v).z, (v).w));    \
        if (m_ > (b)) {                                                      \
            (b) = m_;                                                        \
            (idx) = ((v).x == m_) ? (k)                                      \
                  : ((v).y == m_) ? (k) + 1                                  \
                  : ((v).z == m_) ? (k) + 2                                  \
                  :                 (k) + 3;                                 \
        }                                                                    \
    } while (0)

__global__ __launch_bounds__(BLOCK) void rowmax_argmax_kernel(
    const float* __restrict__ logits, float* __restrict__ out, int S, int V) {
    const int row = blockIdx.x;
    const float* rp = logits + (size_t)row * (size_t)V;

    // Alignment peel: leading elements until 16B-aligned (V % 4 != 0, so
    // each row has its own phase).
    int head = (int)(((16u - ((uintptr_t)rp & 15u)) & 15u) >> 2);
    if (head > V) head = V;
    const int nvec = (V - head) >> 2;
    const int tail_start = head + (nvec << 2);
    const int ntail = V - tail_start;

    const int tid = threadIdx.x;

    // Four independent (val, idx) chains; each chain visits strictly
    // increasing indices so strict '>' keeps first occurrence per chain.
    float b0 = -INFINITY, b1 = -INFINITY, b2 = -INFINITY, b3 = -INFINITY;
    int i0 = 0x7fffffff, i1 = 0x7fffffff, i2 = 0x7fffffff, i3 = 0x7fffffff;

    if (tid < head) { b0 = rp[tid]; i0 = tid; }

    const floatx4* __restrict__ vp = (const floatx4*)(rp + head);
    int i = tid;
    for (; i + 3 * BLOCK < nvec; i += 4 * BLOCK) {
        const floatx4 a = ntload(vp + i);
        const floatx4 b = ntload(vp + i + BLOCK);
        const floatx4 c = ntload(vp + i + 2 * BLOCK);
        const floatx4 d = ntload(vp + i + 3 * BLOCK);
        const int ka = head + (i << 2);
        const int kb = head + ((i + BLOCK) << 2);
        const int kc = head + ((i + 2 * BLOCK) << 2);
        const int kd = head + ((i + 3 * BLOCK) << 2);
        CHAIN_STEP(a, ka, b0, i0);
        CHAIN_STEP(b, kb, b1, i1);
        CHAIN_STEP(c, kc, b2, i2);
        CHAIN_STEP(d, kd, b3, i3);
    }
    for (; i < nvec; i += BLOCK) {   // remainder on chain 0 (increasing idx)
        const floatx4 a = ntload(vp + i);
        const int ka = head + (i << 2);
        CHAIN_STEP(a, ka, b0, i0);
    }
    if (tid < ntail) {               // scalar tail (largest indices, last)
        const float v = rp[tail_start + tid];
        if (v > b0) { b0 = v; i0 = tail_start + tid; }
    }

    // Merge chains: greater val, or equal val with lower index.
    float best = b0; int bidx = i0;
    if (b1 > best || (b1 == best && i1 < bidx)) { best = b1; bidx = i1; }
    if (b2 > best || (b2 == best && i2 < bidx)) { best = b2; bidx = i2; }
    if (b3 > best || (b3 == best && i3 < bidx)) { best = b3; bidx = i3; }

    // Wave (64-lane) reduction.
    #pragma unroll
    for (int off = 32; off >= 1; off >>= 1) {
        const float ov = __shfl_down(best, off, 64);
        const int   oi = __shfl_down(bidx, off, 64);
        if (ov > best || (ov == best && oi < bidx)) { best = ov; bidx = oi; }
    }

    // Cross-wave reduction via LDS (BLOCK/64 waves).
    __shared__ float s_val[BLOCK / 64];
    __shared__ int   s_idx[BLOCK / 64];
    const int wave = tid >> 6;
    const int lane = tid & 63;
    if (lane == 0) { s_val[wave] = best; s_idx[wave] = bidx; }
    __syncthreads();

    if (tid == 0) {
        float fb = s_val[0];
        int fi = s_idx[0];
        #pragma unroll
        for (int w = 1; w < BLOCK / 64; ++w) {
            const float ov = s_val[w];
            const int   oi = s_idx[w];
            if (ov > fb || (ov == fb && oi < fi)) { fb = ov; fi = oi; }
        }
        out[row]     = (float)fi;  // token index, exact as float (< 2^24)
        out[S + row] = fb;         // score
    }
}

extern "C" void kernel_launch(void* const* d_in, const int* in_sizes, int n_in,
                              void* d_out, int out_size, void* d_ws, size_t ws_size,
                              hipStream_t stream) {
    const float* logits = (const float*)d_in[0];
    float* out = (float*)d_out;

    const int S = out_size / 2;              // 512 rows
    const int V = in_sizes[0] / S;           // 50257 vocab

    rowmax_argmax_kernel<<<S, BLOCK, 0, stream>>>(logits, out, S, V);
}